// Round 11
// baseline (383.068 us; speedup 1.0000x reference)
//
#include <hip/hip_runtime.h>
#include <hip/hip_bf16.h>

static constexpr int NG = 512;   // NUM_GRAPHS

typedef __attribute__((ext_vector_type(8))) short bf16x8;
typedef __attribute__((ext_vector_type(4))) float f32x4;

__device__ inline ushort f2bf(float f) {
    union { float f; uint u; } v; v.f = f;
    uint r = (v.u + 0x7FFF + ((v.u >> 16) & 1)) >> 16;   // RNE
    return (ushort)r;
}
__device__ inline float bf2f(ushort h) {
    union { uint u; float f; } v; v.u = (uint)h << 16;
    return v.f;
}
__device__ inline float bflo(uint g) { return bf2f((ushort)(g & 0xFFFF)); }
__device__ inline float bfhi(uint g) { return bf2f((ushort)(g >> 16)); }

// ---------------- bucketed CSR build ----------------
// bucket b = dst window [b*512,(b+1)*512); pairs stored in region [b*CAP, b*CAP+count)
static constexpr int EPW = 4096;   // edges per workgroup (16 per thread)

__global__ __launch_bounds__(256) void partition_kernel(const int* __restrict__ row,
                                                        const int* __restrict__ col,
                                                        int* __restrict__ cursor,   // zero-init; ends = counts
                                                        uint* __restrict__ pairs,
                                                        int E, int nbuk, int CAP) {
    __shared__ int cnt[256];
    __shared__ int gbase[256];
    int tid = threadIdx.x;
    int base = blockIdx.x * EPW;
    for (int b = tid; b < nbuk; b += 256) cnt[b] = 0;
    __syncthreads();
    int rank[16];
    #pragma unroll
    for (int j = 0; j < 16; j++) {
        int e = base + j * 256 + tid;
        rank[j] = (e < E) ? atomicAdd(&cnt[col[e] >> 9], 1) : 0;
    }
    __syncthreads();
    for (int b = tid; b < nbuk; b += 256)
        gbase[b] = cnt[b] ? atomicAdd(&cursor[b], cnt[b]) : 0;
    __syncthreads();
    #pragma unroll
    for (int j = 0; j < 16; j++) {
        int e = base + j * 256 + tid;
        if (e < E) {
            int d = col[e];
            int b = d >> 9;
            uint pos = (uint)(gbase[b] + rank[j]);
            if (pos < (uint)CAP)
                pairs[(size_t)b * CAP + pos] = ((uint)row[e] << 9) | (uint)(d & 511);
        }
    }
}

__global__ __launch_bounds__(256) void bucketscan_kernel(const int* __restrict__ counts,
                                                         int* __restrict__ bbase,
                                                         int nbuk, int E) {
    __shared__ int lds[256];
    int tid = threadIdx.x;
    int v = (tid < nbuk) ? counts[tid] : 0;
    lds[tid] = v;
    __syncthreads();
    #pragma unroll
    for (int off = 1; off < 256; off <<= 1) {
        int t = (tid >= off) ? lds[tid - off] : 0;
        __syncthreads();
        lds[tid] += t;
        __syncthreads();
    }
    if (tid < nbuk) bbase[tid] = lds[tid] - v;
    if (tid == 0) bbase[nbuk] = E;
}

__global__ __launch_bounds__(256) void place_kernel(const uint* __restrict__ pairs,
                                                    const int* __restrict__ counts,
                                                    const int* __restrict__ bbase,
                                                    int* __restrict__ offs,
                                                    float* __restrict__ dinv,
                                                    int* __restrict__ srcs,
                                                    int N, int CAP) {
    __shared__ int deg[512];
    __shared__ int s256[256];
    __shared__ int loc[512];
    __shared__ int cur[512];
    int blk = blockIdx.x;
    int tid = threadIdx.x;
    int nodebase = blk << 9;
    int nend = min(nodebase + 512, N);
    int cnt_b = min(counts[blk], CAP);
    int csr = bbase[blk];
    size_t plo = (size_t)blk * CAP;
    deg[tid] = 0; deg[tid + 256] = 0;
    cur[tid] = 0; cur[tid + 256] = 0;
    __syncthreads();
    for (int e = tid; e < cnt_b; e += 256)
        atomicAdd(&deg[pairs[plo + e] & 511], 1);
    __syncthreads();
    int a0 = deg[2 * tid], a1 = deg[2 * tid + 1];
    s256[tid] = a0 + a1;
    __syncthreads();
    #pragma unroll
    for (int off = 1; off < 256; off <<= 1) {
        int t = (tid >= off) ? s256[tid - off] : 0;
        __syncthreads();
        s256[tid] += t;
        __syncthreads();
    }
    int excl = s256[tid] - (a0 + a1);
    loc[2 * tid]     = excl;
    loc[2 * tid + 1] = excl + a0;
    __syncthreads();
    for (int i = tid; i < 512; i += 256) {
        int node = nodebase + i;
        if (node < N) {
            offs[node] = csr + loc[i];
            dinv[node] = rsqrtf((float)(deg[i] + 1));   // +1 self loop
        }
    }
    if (tid == 0 && nend == N) offs[N] = csr + cnt_b;
    __syncthreads();
    for (int e = tid; e < cnt_b; e += 256) {
        uint p = pairs[plo + e];
        int dl = (int)(p & 511);
        int pos = csr + loc[dl] + atomicAdd(&cur[dl], 1);
        srcs[pos] = (int)(p >> 9);
    }
}

// ---------------- pack W1/W2/W3 into MFMA B-fragment layout (one launch) -----------
__global__ __launch_bounds__(256) void packW_kernel(const float* __restrict__ W1,
                                                    const float* __restrict__ W2,
                                                    const float* __restrict__ W3,
                                                    ushort* __restrict__ Wp1,
                                                    ushort* __restrict__ Wp2,
                                                    ushort* __restrict__ Wp3) {
    int gidx = blockIdx.x * 256 + threadIdx.x;   // 0..6143
    int which = gidx >> 11;                       // 0..2
    int idx = gidx & 2047;
    const float* W = (which == 0) ? W1 : (which == 1) ? W2 : W3;
    ushort* Wp     = (which == 0) ? Wp1 : (which == 1) ? Wp2 : Wp3;
    int lane = idx & 63;
    int nt = (idx >> 6) & 7;
    int kt = idx >> 9;
    int col = nt * 16 + (lane & 15);
    int kbase = kt * 32 + (lane >> 4) * 8;
    ushort* dst = Wp + (size_t)idx * 8;
    #pragma unroll
    for (int j = 0; j < 8; j++)
        dst[j] = f2bf(W[(size_t)(kbase + j) * 128 + col]);
}

// ---------------- MFMA GEMM: C[Mx128] = dinv[r] * (A[Mx128] @ W), bf16 out ---------
// Wp staged in LDS; A fragments prefetched before the barrier.
template<bool F32IN>
__global__ __launch_bounds__(256) void gemm_mfma_kernel(const void* __restrict__ Av,
                                                        const ushort* __restrict__ Wp,
                                                        const float* __restrict__ dinv,
                                                        ushort* __restrict__ C, int M) {
    __shared__ uint4 WpL[2048];   // 32 KB = full packed W
    int tid = threadIdx.x;
    {
        const uint4* s = (const uint4*)Wp;
        #pragma unroll
        for (int j = 0; j < 8; j++) WpL[tid + 256 * j] = s[tid + 256 * j];
    }
    int wave = tid >> 6;
    int lane = tid & 63;
    int r0 = blockIdx.x * 128 + wave * 32;
    bool act = r0 < M;
    const int lrow = lane & 15;
    const int koff = (lane >> 4) * 8;
    bf16x8 a[4][2];
    if (act) {
        #pragma unroll
        for (int kt = 0; kt < 4; kt++) {
            #pragma unroll
            for (int m = 0; m < 2; m++) {
                int r = r0 + 16 * m + lrow;
                r = (r < M) ? r : (M - 1);
                if constexpr (F32IN) {
                    const float* Af = (const float*)Av + (size_t)r * 128 + kt * 32 + koff;
                    float4 v0 = ((const float4*)Af)[0];
                    float4 v1 = ((const float4*)Af)[1];
                    bf16x8 av;
                    av[0] = (short)f2bf(v0.x); av[1] = (short)f2bf(v0.y);
                    av[2] = (short)f2bf(v0.z); av[3] = (short)f2bf(v0.w);
                    av[4] = (short)f2bf(v1.x); av[5] = (short)f2bf(v1.y);
                    av[6] = (short)f2bf(v1.z); av[7] = (short)f2bf(v1.w);
                    a[kt][m] = av;
                } else {
                    a[kt][m] = *(const bf16x8*)((const ushort*)Av + (size_t)r * 128 + kt * 32 + koff);
                }
            }
        }
    }
    __syncthreads();
    if (!act) return;
    const ushort* WL = (const ushort*)WpL;
    f32x4 acc[2][8] = {};
    #pragma unroll
    for (int kt = 0; kt < 4; kt++) {
        #pragma unroll
        for (int nt = 0; nt < 8; nt++) {
            bf16x8 b = *(const bf16x8*)(WL + ((size_t)(kt * 8 + nt) * 64 + lane) * 8);
            acc[0][nt] = __builtin_amdgcn_mfma_f32_16x16x32_bf16(a[kt][0], b, acc[0][nt], 0, 0, 0);
            acc[1][nt] = __builtin_amdgcn_mfma_f32_16x16x32_bf16(a[kt][1], b, acc[1][nt], 0, 0, 0);
        }
    }
    // C/D layout: col = lane&15, row = (lane>>4)*4 + reg   [verified m89]
    #pragma unroll
    for (int m = 0; m < 2; m++) {
        int rbase = r0 + 16 * m + (lane >> 4) * 4;
        int c0 = lane & 15;
        float dsc[4];
        #pragma unroll
        for (int r = 0; r < 4; r++)
            dsc[r] = (rbase + r < M) ? dinv[rbase + r] : 0.0f;
        #pragma unroll
        for (int nt = 0; nt < 8; nt++) {
            #pragma unroll
            for (int r = 0; r < 4; r++) {
                int rr = rbase + r;
                if (rr < M) C[(size_t)rr * 128 + nt * 16 + c0] = f2bf(acc[m][nt][r] * dsc[r]);
            }
        }
    }
}

// ---------------- aggregation on dinv-prescaled h' ----------------
// out[d] = relu(dinv[d] * (h'[d] + sum_{s in N(d)} h'[s]) + bias)
// TWO nodes per wave: half-wave (32 lanes x uint2 = 256B) per node -> ~2x rows in flight
__global__ __launch_bounds__(256) void agg_kernel(const ushort* __restrict__ h,
                                                  const int* __restrict__ offsets,
                                                  const int* __restrict__ srcs,
                                                  const float* __restrict__ dinv,
                                                  const float* __restrict__ bias,
                                                  ushort* __restrict__ out, int n) {
    int gw   = (int)((blockIdx.x * blockDim.x + threadIdx.x) >> 6);
    int lane = threadIdx.x & 63;
    int half = lane >> 5;
    int l32  = lane & 31;
    int node = gw * 2 + half;
    bool active = node < n;
    int nodec = active ? node : (n - 1);
    int s0 = offsets[nodec];
    int s1 = active ? offsets[nodec + 1] : s0;
    int deg = s1 - s0;
    float di = dinv[nodec];
    const uint2* hrow = (const uint2*)h;   // 32 x uint2 per row
    uint2 hv = hrow[(size_t)nodec * 32 + l32];
    float a0 = bflo(hv.x), a1 = bfhi(hv.x);
    float a2 = bflo(hv.y), a3 = bfhi(hv.y);
    int dmax = max(__shfl(deg, 0), __shfl(deg, 32));
    for (int base = 0; base < dmax; base += 16) {
        uint2 gI[16];
        #pragma unroll
        for (int j = 0; j < 16; j++) {
            int e = s0 + base + j;
            if (e < s1) {
                int s = srcs[e];
                gI[j] = hrow[(size_t)s * 32 + l32];
            } else {
                gI[j] = make_uint2(0u, 0u);
            }
        }
        #pragma unroll
        for (int j = 0; j < 16; j++) {
            a0 += bflo(gI[j].x); a1 += bfhi(gI[j].x);
            a2 += bflo(gI[j].y); a3 += bfhi(gI[j].y);
        }
    }
    if (active) {
        float4 b4 = ((const float4*)bias)[l32];
        a0 = fmaxf(fmaf(a0, di, b4.x), 0.0f);
        a1 = fmaxf(fmaf(a1, di, b4.y), 0.0f);
        a2 = fmaxf(fmaf(a2, di, b4.z), 0.0f);
        a3 = fmaxf(fmaf(a3, di, b4.w), 0.0f);
        uint2 o;
        o.x = (uint)f2bf(a0) | ((uint)f2bf(a1) << 16);
        o.y = (uint)f2bf(a2) | ((uint)f2bf(a3) << 16);
        ((uint2*)out)[(size_t)node * 32 + l32] = o;
    }
}

// ---------------- fused mean-pool + MLP per graph (batch sorted) ----------------
__global__ __launch_bounds__(512) void pool_mlp_kernel(const ushort* __restrict__ h,
                                                       const int* __restrict__ batch,
                                                       const float* __restrict__ Wm1,
                                                       const float* __restrict__ bm1,
                                                       const float* __restrict__ Wm2,
                                                       const float* __restrict__ bm2,
                                                       float* __restrict__ out, int n) {
    int g = blockIdx.x;
    int lo = 0, hi = n;
    while (lo < hi) { int mid = (lo + hi) >> 1; if (batch[mid] < g) lo = mid + 1; else hi = mid; }
    int start = lo;
    lo = 0; hi = n;
    while (lo < hi) { int mid = (lo + hi) >> 1; if (batch[mid] < g + 1) lo = mid + 1; else hi = mid; }
    int end = lo;

    int t  = threadIdx.x;
    int c2 = t & 63;
    int rg = t >> 6;
    const uint* hu = (const uint*)h;
    float sx = 0.0f, sy = 0.0f;
    int i = start + rg;
    for (; i + 24 < end; i += 32) {
        uint g0 = hu[(size_t)i * 64 + c2];
        uint g1 = hu[(size_t)(i + 8) * 64 + c2];
        uint g2 = hu[(size_t)(i + 16) * 64 + c2];
        uint g3 = hu[(size_t)(i + 24) * 64 + c2];
        sx += bflo(g0); sy += bfhi(g0);
        sx += bflo(g1); sy += bfhi(g1);
        sx += bflo(g2); sy += bfhi(g2);
        sx += bflo(g3); sy += bfhi(g3);
    }
    for (; i < end; i += 8) {
        uint gg = hu[(size_t)i * 64 + c2];
        sx += bflo(gg); sy += bfhi(gg);
    }
    __shared__ float lsx[512];
    __shared__ float lsy[512];
    __shared__ float p[128];
    __shared__ float z[64];
    lsx[t] = sx; lsy[t] = sy;
    __syncthreads();
    if (rg == 0) {   // t < 64
        float ax = lsx[c2], ay = lsy[c2];
        #pragma unroll
        for (int k = 1; k < 8; k++) {
            ax += lsx[c2 + 64 * k];
            ay += lsy[c2 + 64 * k];
        }
        float cnt = fmaxf((float)(end - start), 1.0f);
        p[2 * c2]     = ax / cnt;
        p[2 * c2 + 1] = ay / cnt;
    }
    __syncthreads();
    if (t < 64) {
        float acc = bm1[t];
        #pragma unroll 8
        for (int k = 0; k < 128; k++) acc = fmaf(p[k], Wm1[k * 64 + t], acc);
        z[t] = fmaxf(acc, 0.0f);
    }
    __syncthreads();
    if (t < 32) {
        float o = bm2[t];
        #pragma unroll 8
        for (int k = 0; k < 64; k++) o = fmaf(z[k], Wm2[k * 32 + t], o);
        out[(size_t)g * 32 + t] = o;
    }
}

extern "C" void kernel_launch(void* const* d_in, const int* in_sizes, int n_in,
                              void* d_out, int out_size, void* d_ws, size_t ws_size,
                              hipStream_t stream) {
    const float* x    = (const float*)d_in[0];
    const int*   ei   = (const int*)d_in[1];
    const int*   batch= (const int*)d_in[2];
    const float* W1   = (const float*)d_in[3];
    const float* b1   = (const float*)d_in[4];
    const float* W2   = (const float*)d_in[5];
    const float* b2   = (const float*)d_in[6];
    const float* W3   = (const float*)d_in[7];
    const float* b3   = (const float*)d_in[8];
    const float* Wm1  = (const float*)d_in[9];
    const float* bm1  = (const float*)d_in[10];
    const float* Wm2  = (const float*)d_in[11];
    const float* bm2  = (const float*)d_in[12];
    float* out = (float*)d_out;

    int N = in_sizes[0] / 128;
    int E = in_sizes[1] / 2;
    const int* row = ei;       // sources
    const int* col = ei + E;   // targets

    int NBUK = (N + 511) / 512;               // dst buckets (196 <= 256)
    int CAP  = ((E + NBUK - 1) / NBUK) * 2;   // 2x mean bucket size
    int EW   = (E + EPW - 1) / EPW;

    char* w = (char*)d_ws;
    auto alloc = [&](size_t bytes) -> char* {
        char* p = w;
        w += (bytes + 255) & ~(size_t)255;
        return p;
    };
    int*    offs    = (int*)   alloc((size_t)(N + 1) * 4);
    float*  dinv    = (float*) alloc((size_t)N * 4);
    int*    srcs    = (int*)   alloc((size_t)E * 4);
    uint*   pairs   = (uint*)  alloc((size_t)NBUK * CAP * 4);
    ushort* hA      = (ushort*)alloc((size_t)N * 128 * 2);
    ushort* hB      = (ushort*)alloc((size_t)N * 128 * 2);
    int*    cursor  = (int*)   alloc((size_t)256 * 4);
    int*    bbase   = (int*)   alloc((size_t)257 * 4);
    ushort* Wp1     = (ushort*)alloc((size_t)128 * 128 * 2);
    ushort* Wp2     = (ushort*)alloc((size_t)128 * 128 * 2);
    ushort* Wp3     = (ushort*)alloc((size_t)128 * 128 * 2);
    (void)ws_size; (void)n_in; (void)out_size;

    hipMemsetAsync(cursor, 0, (size_t)256 * 4, stream);

    partition_kernel<<<EW, 256, 0, stream>>>(row, col, cursor, pairs, E, NBUK, CAP);
    bucketscan_kernel<<<1, 256, 0, stream>>>(cursor, bbase, NBUK, E);
    place_kernel<<<NBUK, 256, 0, stream>>>(pairs, cursor, bbase, offs, dinv, srcs, N, CAP);

    packW_kernel<<<24, 256, 0, stream>>>(W1, W2, W3, Wp1, Wp2, Wp3);

    int gemmBlocks = (N + 127) / 128;
    int aggBlocks  = (N + 7) / 8;   // 4 waves/block, 2 nodes/wave

    gemm_mfma_kernel<true><<<gemmBlocks, 256, 0, stream>>>(x, Wp1, dinv, hA, N);
    agg_kernel<<<aggBlocks, 256, 0, stream>>>(hA, offs, srcs, dinv, b1, hB, N);

    gemm_mfma_kernel<false><<<gemmBlocks, 256, 0, stream>>>(hB, Wp2, dinv, hA, N);
    agg_kernel<<<aggBlocks, 256, 0, stream>>>(hA, offs, srcs, dinv, b2, hB, N);

    gemm_mfma_kernel<false><<<gemmBlocks, 256, 0, stream>>>(hB, Wp3, dinv, hA, N);
    agg_kernel<<<aggBlocks, 256, 0, stream>>>(hA, offs, srcs, dinv, b3, hB, N);

    pool_mlp_kernel<<<NG, 512, 0, stream>>>(hB, batch, Wm1, bm1, Wm2, bm2, out, N);
}

// Round 12
// 335.126 us; speedup vs baseline: 1.1431x; 1.1431x over previous
//
#include <hip/hip_runtime.h>
#include <hip/hip_bf16.h>

static constexpr int NG = 512;   // NUM_GRAPHS

typedef __attribute__((ext_vector_type(8))) short bf16x8;
typedef __attribute__((ext_vector_type(4))) float f32x4;

__device__ inline ushort f2bf(float f) {
    union { float f; uint u; } v; v.f = f;
    uint r = (v.u + 0x7FFF + ((v.u >> 16) & 1)) >> 16;   // RNE
    return (ushort)r;
}
__device__ inline float bf2f(ushort h) {
    union { uint u; float f; } v; v.u = (uint)h << 16;
    return v.f;
}
__device__ inline float bflo(uint g) { return bf2f((ushort)(g & 0xFFFF)); }
__device__ inline float bfhi(uint g) { return bf2f((ushort)(g >> 16)); }

// ---------------- bucketed CSR build ----------------
// bucket b = dst window [b*512,(b+1)*512); pairs stored in region [b*CAP, b*CAP+count)
static constexpr int EPW = 4096;   // edges per workgroup (16 per thread)

__global__ __launch_bounds__(256) void partition_kernel(const int* __restrict__ row,
                                                        const int* __restrict__ col,
                                                        int* __restrict__ cursor,   // zero-init; ends = counts
                                                        uint* __restrict__ pairs,
                                                        int E, int nbuk, int CAP) {
    __shared__ int cnt[256];
    __shared__ int gbase[256];
    int tid = threadIdx.x;
    int base = blockIdx.x * EPW;
    for (int b = tid; b < nbuk; b += 256) cnt[b] = 0;
    __syncthreads();
    int rank[16];
    #pragma unroll
    for (int j = 0; j < 16; j++) {
        int e = base + j * 256 + tid;
        rank[j] = (e < E) ? atomicAdd(&cnt[col[e] >> 9], 1) : 0;
    }
    __syncthreads();
    for (int b = tid; b < nbuk; b += 256)
        gbase[b] = cnt[b] ? atomicAdd(&cursor[b], cnt[b]) : 0;
    __syncthreads();
    #pragma unroll
    for (int j = 0; j < 16; j++) {
        int e = base + j * 256 + tid;
        if (e < E) {
            int d = col[e];
            int b = d >> 9;
            uint pos = (uint)(gbase[b] + rank[j]);
            if (pos < (uint)CAP)
                pairs[(size_t)b * CAP + pos] = ((uint)row[e] << 9) | (uint)(d & 511);
        }
    }
}

__global__ __launch_bounds__(256) void bucketscan_kernel(const int* __restrict__ counts,
                                                         int* __restrict__ bbase,
                                                         int nbuk, int E) {
    __shared__ int lds[256];
    int tid = threadIdx.x;
    int v = (tid < nbuk) ? counts[tid] : 0;
    lds[tid] = v;
    __syncthreads();
    #pragma unroll
    for (int off = 1; off < 256; off <<= 1) {
        int t = (tid >= off) ? lds[tid - off] : 0;
        __syncthreads();
        lds[tid] += t;
        __syncthreads();
    }
    if (tid < nbuk) bbase[tid] = lds[tid] - v;
    if (tid == 0) bbase[nbuk] = E;
}

__global__ __launch_bounds__(256) void place_kernel(const uint* __restrict__ pairs,
                                                    const int* __restrict__ counts,
                                                    const int* __restrict__ bbase,
                                                    int* __restrict__ offs,
                                                    float* __restrict__ dinv,
                                                    int* __restrict__ srcs,
                                                    int N, int CAP) {
    __shared__ int deg[512];
    __shared__ int s256[256];
    __shared__ int loc[512];
    __shared__ int cur[512];
    int blk = blockIdx.x;
    int tid = threadIdx.x;
    int nodebase = blk << 9;
    int nend = min(nodebase + 512, N);
    int cnt_b = min(counts[blk], CAP);
    int csr = bbase[blk];
    size_t plo = (size_t)blk * CAP;
    deg[tid] = 0; deg[tid + 256] = 0;
    cur[tid] = 0; cur[tid + 256] = 0;
    __syncthreads();
    for (int e = tid; e < cnt_b; e += 256)
        atomicAdd(&deg[pairs[plo + e] & 511], 1);
    __syncthreads();
    int a0 = deg[2 * tid], a1 = deg[2 * tid + 1];
    s256[tid] = a0 + a1;
    __syncthreads();
    #pragma unroll
    for (int off = 1; off < 256; off <<= 1) {
        int t = (tid >= off) ? s256[tid - off] : 0;
        __syncthreads();
        s256[tid] += t;
        __syncthreads();
    }
    int excl = s256[tid] - (a0 + a1);
    loc[2 * tid]     = excl;
    loc[2 * tid + 1] = excl + a0;
    __syncthreads();
    for (int i = tid; i < 512; i += 256) {
        int node = nodebase + i;
        if (node < N) {
            offs[node] = csr + loc[i];
            dinv[node] = rsqrtf((float)(deg[i] + 1));   // +1 self loop
        }
    }
    if (tid == 0 && nend == N) offs[N] = csr + cnt_b;
    __syncthreads();
    for (int e = tid; e < cnt_b; e += 256) {
        uint p = pairs[plo + e];
        int dl = (int)(p & 511);
        int pos = csr + loc[dl] + atomicAdd(&cur[dl], 1);
        srcs[pos] = (int)(p >> 9);
    }
}

// ---------------- pack W1/W2/W3 into MFMA B-fragment layout (one launch) -----------
__global__ __launch_bounds__(256) void packW_kernel(const float* __restrict__ W1,
                                                    const float* __restrict__ W2,
                                                    const float* __restrict__ W3,
                                                    ushort* __restrict__ Wp1,
                                                    ushort* __restrict__ Wp2,
                                                    ushort* __restrict__ Wp3) {
    int gidx = blockIdx.x * 256 + threadIdx.x;   // 0..6143
    int which = gidx >> 11;                       // 0..2
    int idx = gidx & 2047;
    const float* W = (which == 0) ? W1 : (which == 1) ? W2 : W3;
    ushort* Wp     = (which == 0) ? Wp1 : (which == 1) ? Wp2 : Wp3;
    int lane = idx & 63;
    int nt = (idx >> 6) & 7;
    int kt = idx >> 9;
    int col = nt * 16 + (lane & 15);
    int kbase = kt * 32 + (lane >> 4) * 8;
    ushort* dst = Wp + (size_t)idx * 8;
    #pragma unroll
    for (int j = 0; j < 8; j++)
        dst[j] = f2bf(W[(size_t)(kbase + j) * 128 + col]);
}

// ---------------- MFMA GEMM: C[Mx128] = dinv[r] * (A[Mx128] @ W), bf16 out ---------
// Wp staged in LDS; A fragments prefetched before the barrier.
template<bool F32IN>
__global__ __launch_bounds__(256) void gemm_mfma_kernel(const void* __restrict__ Av,
                                                        const ushort* __restrict__ Wp,
                                                        const float* __restrict__ dinv,
                                                        ushort* __restrict__ C, int M) {
    __shared__ uint4 WpL[2048];   // 32 KB = full packed W
    int tid = threadIdx.x;
    {
        const uint4* s = (const uint4*)Wp;
        #pragma unroll
        for (int j = 0; j < 8; j++) WpL[tid + 256 * j] = s[tid + 256 * j];
    }
    int wave = tid >> 6;
    int lane = tid & 63;
    int r0 = blockIdx.x * 128 + wave * 32;
    bool act = r0 < M;
    const int lrow = lane & 15;
    const int koff = (lane >> 4) * 8;
    bf16x8 a[4][2];
    if (act) {
        #pragma unroll
        for (int kt = 0; kt < 4; kt++) {
            #pragma unroll
            for (int m = 0; m < 2; m++) {
                int r = r0 + 16 * m + lrow;
                r = (r < M) ? r : (M - 1);
                if constexpr (F32IN) {
                    const float* Af = (const float*)Av + (size_t)r * 128 + kt * 32 + koff;
                    float4 v0 = ((const float4*)Af)[0];
                    float4 v1 = ((const float4*)Af)[1];
                    bf16x8 av;
                    av[0] = (short)f2bf(v0.x); av[1] = (short)f2bf(v0.y);
                    av[2] = (short)f2bf(v0.z); av[3] = (short)f2bf(v0.w);
                    av[4] = (short)f2bf(v1.x); av[5] = (short)f2bf(v1.y);
                    av[6] = (short)f2bf(v1.z); av[7] = (short)f2bf(v1.w);
                    a[kt][m] = av;
                } else {
                    a[kt][m] = *(const bf16x8*)((const ushort*)Av + (size_t)r * 128 + kt * 32 + koff);
                }
            }
        }
    }
    __syncthreads();
    if (!act) return;
    const ushort* WL = (const ushort*)WpL;
    f32x4 acc[2][8] = {};
    #pragma unroll
    for (int kt = 0; kt < 4; kt++) {
        #pragma unroll
        for (int nt = 0; nt < 8; nt++) {
            bf16x8 b = *(const bf16x8*)(WL + ((size_t)(kt * 8 + nt) * 64 + lane) * 8);
            acc[0][nt] = __builtin_amdgcn_mfma_f32_16x16x32_bf16(a[kt][0], b, acc[0][nt], 0, 0, 0);
            acc[1][nt] = __builtin_amdgcn_mfma_f32_16x16x32_bf16(a[kt][1], b, acc[1][nt], 0, 0, 0);
        }
    }
    // C/D layout: col = lane&15, row = (lane>>4)*4 + reg   [verified m89]
    #pragma unroll
    for (int m = 0; m < 2; m++) {
        int rbase = r0 + 16 * m + (lane >> 4) * 4;
        int c0 = lane & 15;
        float dsc[4];
        #pragma unroll
        for (int r = 0; r < 4; r++)
            dsc[r] = (rbase + r < M) ? dinv[rbase + r] : 0.0f;
        #pragma unroll
        for (int nt = 0; nt < 8; nt++) {
            #pragma unroll
            for (int r = 0; r < 4; r++) {
                int rr = rbase + r;
                if (rr < M) C[(size_t)rr * 128 + nt * 16 + c0] = f2bf(acc[m][nt][r] * dsc[r]);
            }
        }
    }
}

// ---------------- aggregation on dinv-prescaled h' (R10 winner) ----------------
// out[d] = relu(dinv[d] * (h'[d] + sum_{s in N(d)} h'[s]) + bias)
// one wave per node; wid/srcs forced wave-uniform (readfirstlane) -> scalar addressing
__global__ __launch_bounds__(256) void agg_kernel(const ushort* __restrict__ h,
                                                  const int* __restrict__ offsets,
                                                  const int* __restrict__ srcs,
                                                  const float* __restrict__ dinv,
                                                  const float* __restrict__ bias,
                                                  ushort* __restrict__ out, int n) {
    int wid  = (int)((blockIdx.x * blockDim.x + threadIdx.x) >> 6);
    int lane = threadIdx.x & 63;
    if (wid >= n) return;
    wid = __builtin_amdgcn_readfirstlane(wid);   // provably wave-uniform
    int s0 = offsets[wid], s1 = offsets[wid + 1];
    float di = dinv[wid];
    const uint* hrow = (const uint*)h;
    uint hv = hrow[(size_t)wid * 64 + lane];
    float ax = bflo(hv), ay = bfhi(hv);   // self term h'[d]
    float bx = 0.0f, by = 0.0f;
    int e = s0;
    for (; e + 16 <= s1; e += 16) {
        int  sI[16];
        uint gI[16];
        #pragma unroll
        for (int j = 0; j < 16; j++) sI[j] = __builtin_amdgcn_readfirstlane(srcs[e + j]);
        #pragma unroll
        for (int j = 0; j < 16; j++) gI[j] = hrow[(size_t)sI[j] * 64 + lane];
        #pragma unroll
        for (int j = 0; j < 16; j += 2) {
            ax += bflo(gI[j]);     ay += bfhi(gI[j]);
            bx += bflo(gI[j + 1]); by += bfhi(gI[j + 1]);
        }
    }
    if (e + 8 <= s1) {
        int  sI[8];
        uint gI[8];
        #pragma unroll
        for (int j = 0; j < 8; j++) sI[j] = __builtin_amdgcn_readfirstlane(srcs[e + j]);
        #pragma unroll
        for (int j = 0; j < 8; j++) gI[j] = hrow[(size_t)sI[j] * 64 + lane];
        #pragma unroll
        for (int j = 0; j < 8; j += 2) {
            ax += bflo(gI[j]);     ay += bfhi(gI[j]);
            bx += bflo(gI[j + 1]); by += bfhi(gI[j + 1]);
        }
        e += 8;
    }
    if (e + 4 <= s1) {
        int  sI[4];
        uint gI[4];
        #pragma unroll
        for (int j = 0; j < 4; j++) sI[j] = __builtin_amdgcn_readfirstlane(srcs[e + j]);
        #pragma unroll
        for (int j = 0; j < 4; j++) gI[j] = hrow[(size_t)sI[j] * 64 + lane];
        #pragma unroll
        for (int j = 0; j < 4; j += 2) {
            ax += bflo(gI[j]);     ay += bfhi(gI[j]);
            bx += bflo(gI[j + 1]); by += bfhi(gI[j + 1]);
        }
        e += 4;
    }
    for (; e < s1; e++) {
        int s = __builtin_amdgcn_readfirstlane(srcs[e]);
        uint g = hrow[(size_t)s * 64 + lane];
        ax += bflo(g);
        ay += bfhi(g);
    }
    ax += bx; ay += by;
    ax = fmaf(ax, di, bias[2 * lane]);
    ay = fmaf(ay, di, bias[2 * lane + 1]);
    ax = fmaxf(ax, 0.0f);
    ay = fmaxf(ay, 0.0f);
    ((uint*)(out + (size_t)wid * 128))[lane] = (uint)f2bf(ax) | ((uint)f2bf(ay) << 16);
}

// ---------------- fused mean-pool + MLP per graph (batch sorted) ----------------
__global__ __launch_bounds__(512) void pool_mlp_kernel(const ushort* __restrict__ h,
                                                       const int* __restrict__ batch,
                                                       const float* __restrict__ Wm1,
                                                       const float* __restrict__ bm1,
                                                       const float* __restrict__ Wm2,
                                                       const float* __restrict__ bm2,
                                                       float* __restrict__ out, int n) {
    int g = blockIdx.x;
    int lo = 0, hi = n;
    while (lo < hi) { int mid = (lo + hi) >> 1; if (batch[mid] < g) lo = mid + 1; else hi = mid; }
    int start = lo;
    lo = 0; hi = n;
    while (lo < hi) { int mid = (lo + hi) >> 1; if (batch[mid] < g + 1) lo = mid + 1; else hi = mid; }
    int end = lo;

    int t  = threadIdx.x;
    int c2 = t & 63;
    int rg = t >> 6;
    const uint* hu = (const uint*)h;
    float sx = 0.0f, sy = 0.0f;
    int i = start + rg;
    for (; i + 24 < end; i += 32) {
        uint g0 = hu[(size_t)i * 64 + c2];
        uint g1 = hu[(size_t)(i + 8) * 64 + c2];
        uint g2 = hu[(size_t)(i + 16) * 64 + c2];
        uint g3 = hu[(size_t)(i + 24) * 64 + c2];
        sx += bflo(g0); sy += bfhi(g0);
        sx += bflo(g1); sy += bfhi(g1);
        sx += bflo(g2); sy += bfhi(g2);
        sx += bflo(g3); sy += bfhi(g3);
    }
    for (; i < end; i += 8) {
        uint gg = hu[(size_t)i * 64 + c2];
        sx += bflo(gg); sy += bfhi(gg);
    }
    __shared__ float lsx[512];
    __shared__ float lsy[512];
    __shared__ float p[128];
    __shared__ float z[64];
    lsx[t] = sx; lsy[t] = sy;
    __syncthreads();
    if (rg == 0) {   // t < 64
        float ax = lsx[c2], ay = lsy[c2];
        #pragma unroll
        for (int k = 1; k < 8; k++) {
            ax += lsx[c2 + 64 * k];
            ay += lsy[c2 + 64 * k];
        }
        float cnt = fmaxf((float)(end - start), 1.0f);
        p[2 * c2]     = ax / cnt;
        p[2 * c2 + 1] = ay / cnt;
    }
    __syncthreads();
    if (t < 64) {
        float acc = bm1[t];
        #pragma unroll 8
        for (int k = 0; k < 128; k++) acc = fmaf(p[k], Wm1[k * 64 + t], acc);
        z[t] = fmaxf(acc, 0.0f);
    }
    __syncthreads();
    if (t < 32) {
        float o = bm2[t];
        #pragma unroll 8
        for (int k = 0; k < 64; k++) o = fmaf(z[k], Wm2[k * 32 + t], o);
        out[(size_t)g * 32 + t] = o;
    }
}

extern "C" void kernel_launch(void* const* d_in, const int* in_sizes, int n_in,
                              void* d_out, int out_size, void* d_ws, size_t ws_size,
                              hipStream_t stream) {
    const float* x    = (const float*)d_in[0];
    const int*   ei   = (const int*)d_in[1];
    const int*   batch= (const int*)d_in[2];
    const float* W1   = (const float*)d_in[3];
    const float* b1   = (const float*)d_in[4];
    const float* W2   = (const float*)d_in[5];
    const float* b2   = (const float*)d_in[6];
    const float* W3   = (const float*)d_in[7];
    const float* b3   = (const float*)d_in[8];
    const float* Wm1  = (const float*)d_in[9];
    const float* bm1  = (const float*)d_in[10];
    const float* Wm2  = (const float*)d_in[11];
    const float* bm2  = (const float*)d_in[12];
    float* out = (float*)d_out;

    int N = in_sizes[0] / 128;
    int E = in_sizes[1] / 2;
    const int* row = ei;       // sources
    const int* col = ei + E;   // targets

    int NBUK = (N + 511) / 512;               // dst buckets (196 <= 256)
    int CAP  = ((E + NBUK - 1) / NBUK) * 2;   // 2x mean bucket size
    int EW   = (E + EPW - 1) / EPW;

    char* w = (char*)d_ws;
    auto alloc = [&](size_t bytes) -> char* {
        char* p = w;
        w += (bytes + 255) & ~(size_t)255;
        return p;
    };
    int*    offs    = (int*)   alloc((size_t)(N + 1) * 4);
    float*  dinv    = (float*) alloc((size_t)N * 4);
    int*    srcs    = (int*)   alloc((size_t)E * 4);
    uint*   pairs   = (uint*)  alloc((size_t)NBUK * CAP * 4);
    ushort* hA      = (ushort*)alloc((size_t)N * 128 * 2);
    ushort* hB      = (ushort*)alloc((size_t)N * 128 * 2);
    int*    cursor  = (int*)   alloc((size_t)256 * 4);
    int*    bbase   = (int*)   alloc((size_t)257 * 4);
    ushort* Wp1     = (ushort*)alloc((size_t)128 * 128 * 2);
    ushort* Wp2     = (ushort*)alloc((size_t)128 * 128 * 2);
    ushort* Wp3     = (ushort*)alloc((size_t)128 * 128 * 2);
    (void)ws_size; (void)n_in; (void)out_size;

    hipMemsetAsync(cursor, 0, (size_t)256 * 4, stream);

    partition_kernel<<<EW, 256, 0, stream>>>(row, col, cursor, pairs, E, NBUK, CAP);
    bucketscan_kernel<<<1, 256, 0, stream>>>(cursor, bbase, NBUK, E);
    place_kernel<<<NBUK, 256, 0, stream>>>(pairs, cursor, bbase, offs, dinv, srcs, N, CAP);

    packW_kernel<<<24, 256, 0, stream>>>(W1, W2, W3, Wp1, Wp2, Wp3);

    int gemmBlocks = (N + 127) / 128;
    int aggBlocks  = (N + 3) / 4;   // 4 waves/block, wave per node

    gemm_mfma_kernel<true><<<gemmBlocks, 256, 0, stream>>>(x, Wp1, dinv, hA, N);
    agg_kernel<<<aggBlocks, 256, 0, stream>>>(hA, offs, srcs, dinv, b1, hB, N);

    gemm_mfma_kernel<false><<<gemmBlocks, 256, 0, stream>>>(hB, Wp2, dinv, hA, N);
    agg_kernel<<<aggBlocks, 256, 0, stream>>>(hA, offs, srcs, dinv, b2, hB, N);

    gemm_mfma_kernel<false><<<gemmBlocks, 256, 0, stream>>>(hB, Wp3, dinv, hA, N);
    agg_kernel<<<aggBlocks, 256, 0, stream>>>(hA, offs, srcs, dinv, b3, hB, N);

    pool_mlp_kernel<<<NG, 512, 0, stream>>>(hB, batch, Wm1, bm1, Wm2, bm2, out, N);
}

// Round 13
// 330.354 us; speedup vs baseline: 1.1596x; 1.0144x over previous
//
#include <hip/hip_runtime.h>
#include <hip/hip_bf16.h>

static constexpr int NG = 512;   // NUM_GRAPHS

typedef __attribute__((ext_vector_type(8))) short bf16x8;
typedef __attribute__((ext_vector_type(4))) float f32x4;

__device__ inline ushort f2bf(float f) {
    union { float f; uint u; } v; v.f = f;
    uint r = (v.u + 0x7FFF + ((v.u >> 16) & 1)) >> 16;   // RNE
    return (ushort)r;
}
__device__ inline float bf2f(ushort h) {
    union { uint u; float f; } v; v.u = (uint)h << 16;
    return v.f;
}
__device__ inline float bflo(uint g) { return bf2f((ushort)(g & 0xFFFF)); }
__device__ inline float bfhi(uint g) { return bf2f((ushort)(g >> 16)); }

// ---------------- bucketed CSR build ----------------
// bucket b = dst window [b*256,(b+1)*256); pairs region [b*CAP, b*CAP+count)
static constexpr int EPW = 4096;   // edges per workgroup (16 per thread)

__global__ __launch_bounds__(256) void partition_kernel(const int* __restrict__ row,
                                                        const int* __restrict__ col,
                                                        int* __restrict__ cursor,   // zero-init; ends = counts
                                                        uint* __restrict__ pairs,
                                                        int E, int nbuk, int CAP) {
    __shared__ int cnt[512];
    __shared__ int gbase[512];
    int tid = threadIdx.x;
    int base = blockIdx.x * EPW;
    for (int b = tid; b < nbuk; b += 256) cnt[b] = 0;
    __syncthreads();
    int rank[16];
    #pragma unroll
    for (int j = 0; j < 16; j++) {
        int e = base + j * 256 + tid;
        rank[j] = (e < E) ? atomicAdd(&cnt[col[e] >> 8], 1) : 0;
    }
    __syncthreads();
    for (int b = tid; b < nbuk; b += 256)
        gbase[b] = cnt[b] ? atomicAdd(&cursor[b], cnt[b]) : 0;
    __syncthreads();
    #pragma unroll
    for (int j = 0; j < 16; j++) {
        int e = base + j * 256 + tid;
        if (e < E) {
            int d = col[e];
            int b = d >> 8;
            uint pos = (uint)(gbase[b] + rank[j]);
            if (pos < (uint)CAP)
                pairs[(size_t)b * CAP + pos] = ((uint)row[e] << 8) | (uint)(d & 255);
        }
    }
}

// chunked single-block scan of nbuk (<=512) bucket counts -> bases
__global__ __launch_bounds__(256) void bucketscan_kernel(const int* __restrict__ counts,
                                                         int* __restrict__ bbase,
                                                         int nbuk, int E) {
    __shared__ int lds[256];
    __shared__ int carry_s;
    int tid = threadIdx.x;
    if (tid == 0) carry_s = 0;
    __syncthreads();
    for (int base = 0; base < nbuk; base += 256) {
        int i = base + tid;
        int v = (i < nbuk) ? counts[i] : 0;
        lds[tid] = v;
        __syncthreads();
        #pragma unroll
        for (int off = 1; off < 256; off <<= 1) {
            int t = (tid >= off) ? lds[tid - off] : 0;
            __syncthreads();
            lds[tid] += t;
            __syncthreads();
        }
        int c = carry_s;
        if (i < nbuk) bbase[i] = c + lds[tid] - v;
        __syncthreads();
        if (tid == 0) carry_s = c + lds[255];
        __syncthreads();
    }
    if (tid == 0) bbase[nbuk] = E;
}

// per bucket (256 nodes): LDS degree histogram, scan -> offs/dinv, place srcs
__global__ __launch_bounds__(256) void place_kernel(const uint* __restrict__ pairs,
                                                    const int* __restrict__ counts,
                                                    const int* __restrict__ bbase,
                                                    int* __restrict__ offs,
                                                    float* __restrict__ dinv,
                                                    int* __restrict__ srcs,
                                                    int N, int CAP) {
    __shared__ int deg[256];
    __shared__ int s256[256];
    __shared__ int cur[256];
    int blk = blockIdx.x;
    int tid = threadIdx.x;
    int nodebase = blk << 8;
    int nend = min(nodebase + 256, N);
    int cnt_b = min(counts[blk], CAP);
    int csr = bbase[blk];
    size_t plo = (size_t)blk * CAP;
    deg[tid] = 0;
    cur[tid] = 0;
    __syncthreads();
    for (int e = tid; e < cnt_b; e += 256)
        atomicAdd(&deg[pairs[plo + e] & 255], 1);
    __syncthreads();
    int a = deg[tid];
    s256[tid] = a;
    __syncthreads();
    #pragma unroll
    for (int off = 1; off < 256; off <<= 1) {
        int t = (tid >= off) ? s256[tid - off] : 0;
        __syncthreads();
        s256[tid] += t;
        __syncthreads();
    }
    int excl = s256[tid] - a;   // exclusive prefix within bucket
    int node = nodebase + tid;
    if (node < N) {
        offs[node] = csr + excl;
        dinv[node] = rsqrtf((float)(a + 1));   // +1 self loop
    }
    if (tid == 0 && nend == N) offs[N] = csr + cnt_b;
    __syncthreads();
    for (int e = tid; e < cnt_b; e += 256) {
        uint p = pairs[plo + e];
        int dl = (int)(p & 255);
        int pos = csr + s256[dl] - deg[dl] + atomicAdd(&cur[dl], 1);
        srcs[pos] = (int)(p >> 8);
    }
}

// ---------------- pack W1/W2/W3 into MFMA B-fragment layout (one launch) -----------
__global__ __launch_bounds__(256) void packW_kernel(const float* __restrict__ W1,
                                                    const float* __restrict__ W2,
                                                    const float* __restrict__ W3,
                                                    ushort* __restrict__ Wp1,
                                                    ushort* __restrict__ Wp2,
                                                    ushort* __restrict__ Wp3) {
    int gidx = blockIdx.x * 256 + threadIdx.x;   // 0..6143
    int which = gidx >> 11;                       // 0..2
    int idx = gidx & 2047;
    const float* W = (which == 0) ? W1 : (which == 1) ? W2 : W3;
    ushort* Wp     = (which == 0) ? Wp1 : (which == 1) ? Wp2 : Wp3;
    int lane = idx & 63;
    int nt = (idx >> 6) & 7;
    int kt = idx >> 9;
    int col = nt * 16 + (lane & 15);
    int kbase = kt * 32 + (lane >> 4) * 8;
    ushort* dst = Wp + (size_t)idx * 8;
    #pragma unroll
    for (int j = 0; j < 8; j++)
        dst[j] = f2bf(W[(size_t)(kbase + j) * 128 + col]);
}

// ---------------- MFMA GEMM: C[Mx128] = dinv[r] * (A[Mx128] @ W), bf16 out ---------
// Wp staged in LDS; A fragments prefetched before the barrier.
template<bool F32IN>
__global__ __launch_bounds__(256) void gemm_mfma_kernel(const void* __restrict__ Av,
                                                        const ushort* __restrict__ Wp,
                                                        const float* __restrict__ dinv,
                                                        ushort* __restrict__ C, int M) {
    __shared__ uint4 WpL[2048];   // 32 KB = full packed W
    int tid = threadIdx.x;
    {
        const uint4* s = (const uint4*)Wp;
        #pragma unroll
        for (int j = 0; j < 8; j++) WpL[tid + 256 * j] = s[tid + 256 * j];
    }
    int wave = tid >> 6;
    int lane = tid & 63;
    int r0 = blockIdx.x * 128 + wave * 32;
    bool act = r0 < M;
    const int lrow = lane & 15;
    const int koff = (lane >> 4) * 8;
    bf16x8 a[4][2];
    if (act) {
        #pragma unroll
        for (int kt = 0; kt < 4; kt++) {
            #pragma unroll
            for (int m = 0; m < 2; m++) {
                int r = r0 + 16 * m + lrow;
                r = (r < M) ? r : (M - 1);
                if constexpr (F32IN) {
                    const float* Af = (const float*)Av + (size_t)r * 128 + kt * 32 + koff;
                    float4 v0 = ((const float4*)Af)[0];
                    float4 v1 = ((const float4*)Af)[1];
                    bf16x8 av;
                    av[0] = (short)f2bf(v0.x); av[1] = (short)f2bf(v0.y);
                    av[2] = (short)f2bf(v0.z); av[3] = (short)f2bf(v0.w);
                    av[4] = (short)f2bf(v1.x); av[5] = (short)f2bf(v1.y);
                    av[6] = (short)f2bf(v1.z); av[7] = (short)f2bf(v1.w);
                    a[kt][m] = av;
                } else {
                    a[kt][m] = *(const bf16x8*)((const ushort*)Av + (size_t)r * 128 + kt * 32 + koff);
                }
            }
        }
    }
    __syncthreads();
    if (!act) return;
    const ushort* WL = (const ushort*)WpL;
    f32x4 acc[2][8] = {};
    #pragma unroll
    for (int kt = 0; kt < 4; kt++) {
        #pragma unroll
        for (int nt = 0; nt < 8; nt++) {
            bf16x8 b = *(const bf16x8*)(WL + ((size_t)(kt * 8 + nt) * 64 + lane) * 8);
            acc[0][nt] = __builtin_amdgcn_mfma_f32_16x16x32_bf16(a[kt][0], b, acc[0][nt], 0, 0, 0);
            acc[1][nt] = __builtin_amdgcn_mfma_f32_16x16x32_bf16(a[kt][1], b, acc[1][nt], 0, 0, 0);
        }
    }
    // C/D layout: col = lane&15, row = (lane>>4)*4 + reg   [verified m89]
    #pragma unroll
    for (int m = 0; m < 2; m++) {
        int rbase = r0 + 16 * m + (lane >> 4) * 4;
        int c0 = lane & 15;
        float dsc[4];
        #pragma unroll
        for (int r = 0; r < 4; r++)
            dsc[r] = (rbase + r < M) ? dinv[rbase + r] : 0.0f;
        #pragma unroll
        for (int nt = 0; nt < 8; nt++) {
            #pragma unroll
            for (int r = 0; r < 4; r++) {
                int rr = rbase + r;
                if (rr < M) C[(size_t)rr * 128 + nt * 16 + c0] = f2bf(acc[m][nt][r] * dsc[r]);
            }
        }
    }
}

// ---------------- aggregation on dinv-prescaled h' ----------------
// out[d] = relu(dinv[d] * (h'[d] + sum_{s in N(d)} h'[s]) + bias)
// one wave per node, scalar addressing; masked 24-batch covers deg<=24 (~98%) in
// ONE latency round (masked slots reload clamped rows -> L1 hits, fmaf(mask,..) adds)
__global__ __launch_bounds__(256) void agg_kernel(const ushort* __restrict__ h,
                                                  const int* __restrict__ offsets,
                                                  const int* __restrict__ srcs,
                                                  const float* __restrict__ dinv,
                                                  const float* __restrict__ bias,
                                                  ushort* __restrict__ out, int n) {
    int wid  = (int)((blockIdx.x * blockDim.x + threadIdx.x) >> 6);
    int lane = threadIdx.x & 63;
    if (wid >= n) return;
    wid = __builtin_amdgcn_readfirstlane(wid);   // provably wave-uniform
    int s0 = offsets[wid], s1 = offsets[wid + 1];
    float di = dinv[wid];
    const uint* hrow = (const uint*)h;
    uint hv = hrow[(size_t)wid * 64 + lane];
    float ax = bflo(hv), ay = bfhi(hv);   // self term h'[d]
    float bx = 0.0f, by = 0.0f;
    {   // masked 24-batch
        int  sI[24];
        uint gI[24];
        #pragma unroll
        for (int j = 0; j < 24; j++) {
            int eec = s0 + j;
            eec = (eec < s1 - 1) ? eec : (s1 - 1);
            eec = (eec > 0) ? eec : 0;
            sI[j] = __builtin_amdgcn_readfirstlane(srcs[eec]);
        }
        #pragma unroll
        for (int j = 0; j < 24; j++) gI[j] = hrow[(size_t)sI[j] * 64 + lane];
        #pragma unroll
        for (int j = 0; j < 24; j += 2) {
            float m0 = (s0 + j     < s1) ? 1.0f : 0.0f;
            float m1 = (s0 + j + 1 < s1) ? 1.0f : 0.0f;
            ax = fmaf(m0, bflo(gI[j]),     ax);
            ay = fmaf(m0, bfhi(gI[j]),     ay);
            bx = fmaf(m1, bflo(gI[j + 1]), bx);
            by = fmaf(m1, bfhi(gI[j + 1]), by);
        }
    }
    int e = s0 + 24;
    for (; e + 8 <= s1; e += 8) {   // tail for deg > 24 (~2% of nodes)
        int  sI[8];
        uint gI[8];
        #pragma unroll
        for (int j = 0; j < 8; j++) sI[j] = __builtin_amdgcn_readfirstlane(srcs[e + j]);
        #pragma unroll
        for (int j = 0; j < 8; j++) gI[j] = hrow[(size_t)sI[j] * 64 + lane];
        #pragma unroll
        for (int j = 0; j < 8; j += 2) {
            ax += bflo(gI[j]);     ay += bfhi(gI[j]);
            bx += bflo(gI[j + 1]); by += bfhi(gI[j + 1]);
        }
    }
    for (; e < s1; e++) {
        int s = __builtin_amdgcn_readfirstlane(srcs[e]);
        uint g = hrow[(size_t)s * 64 + lane];
        ax += bflo(g);
        ay += bfhi(g);
    }
    ax += bx; ay += by;
    float2 bv = ((const float2*)bias)[lane];
    ax = fmaf(ax, di, bv.x);
    ay = fmaf(ay, di, bv.y);
    ax = fmaxf(ax, 0.0f);
    ay = fmaxf(ay, 0.0f);
    ((uint*)(out + (size_t)wid * 128))[lane] = (uint)f2bf(ax) | ((uint)f2bf(ay) << 16);
}

// ---------------- fused mean-pool + MLP per graph (batch sorted) ----------------
__global__ __launch_bounds__(512) void pool_mlp_kernel(const ushort* __restrict__ h,
                                                       const int* __restrict__ batch,
                                                       const float* __restrict__ Wm1,
                                                       const float* __restrict__ bm1,
                                                       const float* __restrict__ Wm2,
                                                       const float* __restrict__ bm2,
                                                       float* __restrict__ out, int n) {
    int g = blockIdx.x;
    int lo = 0, hi = n;
    while (lo < hi) { int mid = (lo + hi) >> 1; if (batch[mid] < g) lo = mid + 1; else hi = mid; }
    int start = lo;
    lo = 0; hi = n;
    while (lo < hi) { int mid = (lo + hi) >> 1; if (batch[mid] < g + 1) lo = mid + 1; else hi = mid; }
    int end = lo;

    int t  = threadIdx.x;
    int c2 = t & 63;
    int rg = t >> 6;
    const uint* hu = (const uint*)h;
    float sx = 0.0f, sy = 0.0f;
    int i = start + rg;
    for (; i + 24 < end; i += 32) {
        uint g0 = hu[(size_t)i * 64 + c2];
        uint g1 = hu[(size_t)(i + 8) * 64 + c2];
        uint g2 = hu[(size_t)(i + 16) * 64 + c2];
        uint g3 = hu[(size_t)(i + 24) * 64 + c2];
        sx += bflo(g0); sy += bfhi(g0);
        sx += bflo(g1); sy += bfhi(g1);
        sx += bflo(g2); sy += bfhi(g2);
        sx += bflo(g3); sy += bfhi(g3);
    }
    for (; i < end; i += 8) {
        uint gg = hu[(size_t)i * 64 + c2];
        sx += bflo(gg); sy += bfhi(gg);
    }
    __shared__ float lsx[512];
    __shared__ float lsy[512];
    __shared__ float p[128];
    __shared__ float z[64];
    lsx[t] = sx; lsy[t] = sy;
    __syncthreads();
    if (rg == 0) {   // t < 64
        float ax = lsx[c2], ay = lsy[c2];
        #pragma unroll
        for (int k = 1; k < 8; k++) {
            ax += lsx[c2 + 64 * k];
            ay += lsy[c2 + 64 * k];
        }
        float cnt = fmaxf((float)(end - start), 1.0f);
        p[2 * c2]     = ax / cnt;
        p[2 * c2 + 1] = ay / cnt;
    }
    __syncthreads();
    if (t < 64) {
        float acc = bm1[t];
        #pragma unroll 8
        for (int k = 0; k < 128; k++) acc = fmaf(p[k], Wm1[k * 64 + t], acc);
        z[t] = fmaxf(acc, 0.0f);
    }
    __syncthreads();
    if (t < 32) {
        float o = bm2[t];
        #pragma unroll 8
        for (int k = 0; k < 64; k++) o = fmaf(z[k], Wm2[k * 32 + t], o);
        out[(size_t)g * 32 + t] = o;
    }
}

extern "C" void kernel_launch(void* const* d_in, const int* in_sizes, int n_in,
                              void* d_out, int out_size, void* d_ws, size_t ws_size,
                              hipStream_t stream) {
    const float* x    = (const float*)d_in[0];
    const int*   ei   = (const int*)d_in[1];
    const int*   batch= (const int*)d_in[2];
    const float* W1   = (const float*)d_in[3];
    const float* b1   = (const float*)d_in[4];
    const float* W2   = (const float*)d_in[5];
    const float* b2   = (const float*)d_in[6];
    const float* W3   = (const float*)d_in[7];
    const float* b3   = (const float*)d_in[8];
    const float* Wm1  = (const float*)d_in[9];
    const float* bm1  = (const float*)d_in[10];
    const float* Wm2  = (const float*)d_in[11];
    const float* bm2  = (const float*)d_in[12];
    float* out = (float*)d_out;

    int N = in_sizes[0] / 128;
    int E = in_sizes[1] / 2;
    const int* row = ei;       // sources
    const int* col = ei + E;   // targets

    int NBUK = (N + 255) / 256;               // dst buckets (391 <= 512)
    int CAP  = ((E + NBUK - 1) / NBUK) * 2;   // 2x mean bucket size
    int EW   = (E + EPW - 1) / EPW;

    char* w = (char*)d_ws;
    auto alloc = [&](size_t bytes) -> char* {
        char* p = w;
        w += (bytes + 255) & ~(size_t)255;
        return p;
    };
    int*    offs    = (int*)   alloc((size_t)(N + 1) * 4);
    float*  dinv    = (float*) alloc((size_t)N * 4);
    int*    srcs    = (int*)   alloc((size_t)E * 4);
    uint*   pairs   = (uint*)  alloc((size_t)NBUK * CAP * 4);
    ushort* hA      = (ushort*)alloc((size_t)N * 128 * 2);
    ushort* hB      = (ushort*)alloc((size_t)N * 128 * 2);
    int*    cursor  = (int*)   alloc((size_t)512 * 4);
    int*    bbase   = (int*)   alloc((size_t)513 * 4);
    ushort* Wp1     = (ushort*)alloc((size_t)128 * 128 * 2);
    ushort* Wp2     = (ushort*)alloc((size_t)128 * 128 * 2);
    ushort* Wp3     = (ushort*)alloc((size_t)128 * 128 * 2);
    (void)ws_size; (void)n_in; (void)out_size;

    hipMemsetAsync(cursor, 0, (size_t)512 * 4, stream);

    partition_kernel<<<EW, 256, 0, stream>>>(row, col, cursor, pairs, E, NBUK, CAP);
    bucketscan_kernel<<<1, 256, 0, stream>>>(cursor, bbase, NBUK, E);
    place_kernel<<<NBUK, 256, 0, stream>>>(pairs, cursor, bbase, offs, dinv, srcs, N, CAP);

    packW_kernel<<<24, 256, 0, stream>>>(W1, W2, W3, Wp1, Wp2, Wp3);

    int gemmBlocks = (N + 127) / 128;
    int aggBlocks  = (N + 3) / 4;   // 4 waves/block, wave per node

    gemm_mfma_kernel<true><<<gemmBlocks, 256, 0, stream>>>(x, Wp1, dinv, hA, N);
    agg_kernel<<<aggBlocks, 256, 0, stream>>>(hA, offs, srcs, dinv, b1, hB, N);

    gemm_mfma_kernel<false><<<gemmBlocks, 256, 0, stream>>>(hB, Wp2, dinv, hA, N);
    agg_kernel<<<aggBlocks, 256, 0, stream>>>(hA, offs, srcs, dinv, b2, hB, N);

    gemm_mfma_kernel<false><<<gemmBlocks, 256, 0, stream>>>(hB, Wp3, dinv, hA, N);
    agg_kernel<<<aggBlocks, 256, 0, stream>>>(hA, offs, srcs, dinv, b3, hB, N);

    pool_mlp_kernel<<<NG, 512, 0, stream>>>(hB, batch, Wm1, bm1, Wm2, bm2, out, N);
}